// Round 1
// baseline (14846.117 us; speedup 1.0000x reference)
//
#include <hip/hip_runtime.h>
#include <hip/hip_bf16.h>

#define B_ 32
#define S_ 64
#define H_ 512
#define V_ 32000
#define T_ 64

typedef __bf16 bf16x8 __attribute__((ext_vector_type(8)));
typedef float f32x4 __attribute__((ext_vector_type(4)));

__device__ __forceinline__ float fast_tanh(float x) {
  float e = __expf(2.0f * x);
  return 1.0f - 2.0f / (e + 1.0f);
}
__device__ __forceinline__ float fast_sigmoid(float x) {
  return 1.0f / (1.0f + __expf(-x));
}

// ---------------- prep kernels ----------------

__global__ __launch_bounds__(256) void k_emb_gather(const int* __restrict__ target,
    const float* __restrict__ emb, float* __restrict__ emb_all) {
  int row = blockIdx.x;                 // t*32 + b
  int t = row >> 5, b = row & 31;
  int tok = (t == 0) ? 0 : target[b * T_ + t - 1];
  const float* src = emb + (size_t)tok * H_;
  float* dst = emb_all + (size_t)row * H_;
  for (int j = threadIdx.x; j < H_; j += 256) dst[j] = src[j];
}

// W2[j][0:512] = W_ih[j][512:1024] (ctx part), W2[j][512:1024] = W_hh[j][0:512]
__global__ __launch_bounds__(256) void k_pack_w2(const float* __restrict__ W_ih,
    const float* __restrict__ W_hh, float* __restrict__ W2) {
  int j = blockIdx.x;                   // 0..1535
  int k4 = threadIdx.x * 4;             // 0..1020
  float4 v;
  if (k4 < 512) v = *(const float4*)(W_ih + (size_t)j * 1024 + 512 + k4);
  else          v = *(const float4*)(W_hh + (size_t)j * 512 + (k4 - 512));
  *(float4*)(W2 + (size_t)j * 1024 + k4) = v;
}

__global__ __launch_bounds__(256) void k_transpose_wq(const float* __restrict__ Wq,
    float* __restrict__ WqT) {
  int k = blockIdx.x;                   // 0..511
  for (int j = threadIdx.x; j < H_; j += 256)
    WqT[(size_t)k * H_ + j] = Wq[(size_t)j * H_ + k];
}

__global__ __launch_bounds__(256) void k_init(const float* __restrict__ ehs,
    float* __restrict__ h0, int* __restrict__ flags) {
  int i = blockIdx.x * 256 + threadIdx.x;
  if (i < B_ * H_) h0[i] = ehs[i];
  if (i < T_) flags[i] = 0;
}

// ---------------- generic fp32 GEMM: C[M,N] = A[M,K] @ B[N,K]^T + bias ----------------
// grid: (N/64, M/64), block 256. K % 16 == 0, lda/ldb % 4 == 0.

__global__ __launch_bounds__(256) void k_gemm_f32(
    const float* __restrict__ A, int lda,
    const float* __restrict__ B, int ldb,
    const float* __restrict__ bias,
    float* __restrict__ C, int ldc, int K) {
  __shared__ float As[16][64];
  __shared__ float Bs[16][64];
  const int tid = threadIdx.x;
  const int tx = tid & 15, ty = tid >> 4;
  const int m0 = blockIdx.y * 64, n0 = blockIdx.x * 64;
  const int r = tid >> 2, c4 = (tid & 3) * 4;
  float acc[4][4] = {};
  for (int k0 = 0; k0 < K; k0 += 16) {
    const float4 av = *(const float4*)(A + (size_t)(m0 + r) * lda + k0 + c4);
    const float4 bv = *(const float4*)(B + (size_t)(n0 + r) * ldb + k0 + c4);
    __syncthreads();
    As[c4 + 0][r] = av.x; As[c4 + 1][r] = av.y; As[c4 + 2][r] = av.z; As[c4 + 3][r] = av.w;
    Bs[c4 + 0][r] = bv.x; Bs[c4 + 1][r] = bv.y; Bs[c4 + 2][r] = bv.z; Bs[c4 + 3][r] = bv.w;
    __syncthreads();
#pragma unroll
    for (int k = 0; k < 16; ++k) {
      const float4 a = *(const float4*)(&As[k][ty * 4]);
      const float4 b = *(const float4*)(&Bs[k][tx * 4]);
      const float a4[4] = {a.x, a.y, a.z, a.w};
      const float b4[4] = {b.x, b.y, b.z, b.w};
#pragma unroll
      for (int i = 0; i < 4; ++i)
#pragma unroll
        for (int j = 0; j < 4; ++j)
          acc[i][j] = fmaf(a4[i], b4[j], acc[i][j]);
    }
  }
  const float4 bb = *(const float4*)(bias + n0 + tx * 4);
#pragma unroll
  for (int i = 0; i < 4; ++i) {
    float4 o;
    o.x = acc[i][0] + bb.x; o.y = acc[i][1] + bb.y;
    o.z = acc[i][2] + bb.z; o.w = acc[i][3] + bb.w;
    *(float4*)(C + (size_t)(m0 + ty * 4 + i) * ldc + n0 + tx * 4) = o;
  }
}

// ---------------- per-step fused attention + GRU ----------------
// blocks 0..31: attention for b = blockIdx; blocks 32..287: gates for 2 hidx each.

__global__ __launch_bounds__(256) void k_step(
    int t,
    const float* __restrict__ hcur, float* __restrict__ hnxt,
    const float* __restrict__ kproj, const float* __restrict__ enc,
    const float* __restrict__ WqT, const float* __restrict__ bq,
    const float* __restrict__ Wv, const float* __restrict__ bv,
    const float* __restrict__ giemb, const float* __restrict__ W2,
    const float* __restrict__ b_hh,
    float* __restrict__ ctx, float* __restrict__ attn_out,
    __hip_bfloat16* __restrict__ Hall, int* __restrict__ flags) {
  __shared__ float smem[2048];
  const int tid = threadIdx.x;
  if (blockIdx.x < 32) {
    // ---- attention for batch b ----
    const int b = blockIdx.x;
    float* h_s = smem;           // 512
    float* q_s = smem + 512;     // 512
    float* red = smem + 1024;    // 256
    float* w_s = smem + 1280;    // 64
    for (int j = tid; j < H_; j += 256) h_s[j] = hcur[b * H_ + j];
    __syncthreads();
    // q = h @ Wq^T + bq  (WqT is [k][j], coalesced over j)
    {
      float a0 = bq[tid], a1 = bq[tid + 256];
      for (int k = 0; k < H_; ++k) {
        const float hv = h_s[k];
        const float* wr = WqT + (size_t)k * H_;
        a0 = fmaf(hv, wr[tid], a0);
        a1 = fmaf(hv, wr[tid + 256], a1);
      }
      q_s[tid] = a0; q_s[tid + 256] = a1;
    }
    __syncthreads();
    // scores[s] = sum_h Wv[h]*tanh(q[h] + kproj[b,s,h]) + bv
    {
      const int s = tid >> 2, part = tid & 3;
      const float* kp = kproj + ((size_t)b * S_ + s) * H_ + part * 128;
      const float* qp = q_s + part * 128;
      const float* wp = Wv + part * 128;
      float sc = 0.f;
      for (int k = 0; k < 128; k += 4) {
        const float4 kv = *(const float4*)(kp + k);
        const float4 qv = *(const float4*)(qp + k);
        const float4 wv = *(const float4*)(wp + k);
        sc = fmaf(wv.x, fast_tanh(qv.x + kv.x), sc);
        sc = fmaf(wv.y, fast_tanh(qv.y + kv.y), sc);
        sc = fmaf(wv.z, fast_tanh(qv.z + kv.z), sc);
        sc = fmaf(wv.w, fast_tanh(qv.w + kv.w), sc);
      }
      red[tid] = sc;
    }
    __syncthreads();
    if (tid < 64) {
      float sc = red[tid * 4] + red[tid * 4 + 1] + red[tid * 4 + 2] + red[tid * 4 + 3] + bv[0];
      float m = sc;
#pragma unroll
      for (int d = 32; d > 0; d >>= 1) m = fmaxf(m, __shfl_xor(m, d, 64));
      const float e = __expf(sc - m);
      float sum = e;
#pragma unroll
      for (int d = 32; d > 0; d >>= 1) sum += __shfl_xor(sum, d, 64);
      const float w = e / sum;
      w_s[tid] = w;
      attn_out[((size_t)b * T_ + t) * S_ + tid] = w;
    }
    __syncthreads();
    // ctx = sum_s w[s] * enc[b,s,:]
#pragma unroll
    for (int jj = 0; jj < 2; ++jj) {
      const int j = tid + jj * 256;
      float a = 0.f;
      for (int s = 0; s < S_; ++s)
        a = fmaf(w_s[s], enc[((size_t)b * S_ + s) * H_ + j], a);
      ctx[b * H_ + j] = a;
    }
    __threadfence();
    __syncthreads();
    if (tid == 0)
      __hip_atomic_fetch_add(&flags[t], 1, __ATOMIC_RELEASE, __HIP_MEMORY_SCOPE_AGENT);
  } else {
    // ---- GRU gates for hidx0, hidx0+1 over all 32 batches ----
    const int gb = blockIdx.x - 32;     // 0..255
    const int hidx0 = gb * 2;
    const int b = tid & 31, ks = tid >> 5;   // ks: 8 k-slots of 128
    float* red = smem;                  // [8][6][32] = 1536
    float acc[2][3] = {{0.f, 0.f, 0.f}, {0.f, 0.f, 0.f}};
    const float* w2r[2][3];
    const int koff = (ks < 4) ? ks * 128 : (ks - 4) * 128 + 512;
#pragma unroll
    for (int hl = 0; hl < 2; ++hl)
#pragma unroll
      for (int g = 0; g < 3; ++g)
        w2r[hl][g] = W2 + (size_t)(g * H_ + hidx0 + hl) * 1024 + koff;

    auto do_acc = [&](const float* xb) {
      for (int k = 0; k < 128; k += 4) {
        const float4 xv = *(const float4*)(xb + k);
#pragma unroll
        for (int hl = 0; hl < 2; ++hl)
#pragma unroll
          for (int g = 0; g < 3; ++g) {
            const float4 w = *(const float4*)(w2r[hl][g] + k);
            acc[hl][g] += xv.x * w.x + xv.y * w.y + xv.z * w.z + xv.w * w.w;
          }
      }
    };
    if (ks >= 4) do_acc(hcur + b * H_ + (ks - 4) * 128);   // h-part: no ctx needed
    if (tid == 0) {
      while (__hip_atomic_load(&flags[t], __ATOMIC_ACQUIRE, __HIP_MEMORY_SCOPE_AGENT) < 32)
        __builtin_amdgcn_s_sleep(16);
    }
    __syncthreads();
    if (ks < 4) do_acc(ctx + b * H_ + ks * 128);           // ctx-part
#pragma unroll
    for (int hl = 0; hl < 2; ++hl)
#pragma unroll
      for (int g = 0; g < 3; ++g)
        red[(ks * 6 + hl * 3 + g) * 32 + b] = acc[hl][g];
    __syncthreads();
    if (tid < 64) {
      const int hl = tid >> 5, b2 = tid & 31;
      const int hidx = hidx0 + hl;
      float sr = 0.f, sz = 0.f, snc = 0.f, snh = 0.f;
#pragma unroll
      for (int k2 = 0; k2 < 8; ++k2) {
        const float vr = red[(k2 * 6 + hl * 3 + 0) * 32 + b2];
        const float vz = red[(k2 * 6 + hl * 3 + 1) * 32 + b2];
        const float vn = red[(k2 * 6 + hl * 3 + 2) * 32 + b2];
        sr += vr; sz += vz;
        if (k2 < 4) snc += vn; else snh += vn;
      }
      const size_t grow = ((size_t)t * B_ + b2) * 1536;
      const float rpre = giemb[grow + hidx] + sr + b_hh[hidx];
      const float zpre = giemb[grow + 512 + hidx] + sz + b_hh[512 + hidx];
      const float in_ = giemb[grow + 1024 + hidx] + snc;          // i_n (b_ih folded)
      const float hn = snh + b_hh[1024 + hidx];                   // h_n
      const float rg = fast_sigmoid(rpre);
      const float zg = fast_sigmoid(zpre);
      const float ng = fast_tanh(in_ + rg * hn);
      const float ho = hcur[b2 * H_ + hidx];
      const float hv = (1.f - zg) * ng + zg * ho;
      hnxt[b2 * H_ + hidx] = hv;
      Hall[((size_t)t * B_ + b2) * H_ + hidx] = __float2bfloat16(hv);
    }
  }
}

// ---------------- logits GEMM: out[b*T+t, :] = Hall[t*B+b, :] @ Wo^T + bo (bf16 MFMA) ----------------
// grid (V/128, 2048/128), block 256 (4 waves), tile 128x128, BK=32.

__global__ __launch_bounds__(256) void k_logits(
    const __hip_bfloat16* __restrict__ Hall, const float* __restrict__ Wo,
    const float* __restrict__ bo, float* __restrict__ out0) {
  __shared__ __hip_bfloat16 Asub[128 * 32];
  __shared__ __hip_bfloat16 Bsub[128 * 32];
  const int tid = threadIdx.x;
  const int lane = tid & 63, wave = tid >> 6;
  const int wr = wave >> 1, wc = wave & 1;
  const int n0 = blockIdx.x * 128, m0 = blockIdx.y * 128;
  f32x4 acc[4][4];
#pragma unroll
  for (int i = 0; i < 4; ++i)
#pragma unroll
    for (int j = 0; j < 4; ++j) acc[i][j] = (f32x4){0.f, 0.f, 0.f, 0.f};

  for (int k0 = 0; k0 < 512; k0 += 32) {
    uint4 a_v[2];
#pragma unroll
    for (int r = 0; r < 2; ++r) {
      const int seg = tid + r * 256;
      const int row = seg >> 2, ks8 = (seg & 3) * 8;
      a_v[r] = *(const uint4*)(Hall + (size_t)(m0 + row) * 512 + k0 + ks8);
    }
    float4 b_v[4];
#pragma unroll
    for (int r = 0; r < 4; ++r) {
      const int idx = tid + r * 256;
      const int n = idx >> 3, kg = (idx & 7) * 4;
      b_v[r] = *(const float4*)(Wo + (size_t)(n0 + n) * 512 + k0 + kg);
    }
    __syncthreads();
#pragma unroll
    for (int r = 0; r < 2; ++r) {
      const int seg = tid + r * 256;
      *(uint4*)(Asub + seg * 8) = a_v[r];
    }
#pragma unroll
    for (int r = 0; r < 4; ++r) {
      const int idx = tid + r * 256;
      const int n = idx >> 3, kg = (idx & 7) * 4;
      union { __hip_bfloat16 h[4]; uint2 u; } cv;
      cv.h[0] = __float2bfloat16(b_v[r].x);
      cv.h[1] = __float2bfloat16(b_v[r].y);
      cv.h[2] = __float2bfloat16(b_v[r].z);
      cv.h[3] = __float2bfloat16(b_v[r].w);
      *(uint2*)(Bsub + n * 32 + kg) = cv.u;
    }
    __syncthreads();
    bf16x8 af[4], bfr[4];
#pragma unroll
    for (int mi = 0; mi < 4; ++mi)
      af[mi] = *(const bf16x8*)(Asub + (wr * 64 + mi * 16 + (lane & 15)) * 32 + (lane >> 4) * 8);
#pragma unroll
    for (int ni = 0; ni < 4; ++ni)
      bfr[ni] = *(const bf16x8*)(Bsub + (wc * 64 + ni * 16 + (lane & 15)) * 32 + (lane >> 4) * 8);
#pragma unroll
    for (int mi = 0; mi < 4; ++mi)
#pragma unroll
      for (int ni = 0; ni < 4; ++ni)
        acc[mi][ni] = __builtin_amdgcn_mfma_f32_16x16x32_bf16(af[mi], bfr[ni], acc[mi][ni], 0, 0, 0);
  }
  const int r4 = (lane >> 4) * 4, cc = lane & 15;
#pragma unroll
  for (int ni = 0; ni < 4; ++ni) {
    const int col = n0 + wc * 64 + ni * 16 + cc;
    const float bias = bo[col];
#pragma unroll
    for (int mi = 0; mi < 4; ++mi) {
#pragma unroll
      for (int i = 0; i < 4; ++i) {
        const int mrow = m0 + wr * 64 + mi * 16 + r4 + i;   // = t*32 + b
        const int orow = ((mrow & 31) << 6) | (mrow >> 5);  // = b*64 + t
        out0[(size_t)orow * V_ + col] = acc[mi][ni][i] + bias;
      }
    }
  }
}

// ---------------- in-place log_softmax over V, one row per block ----------------

__global__ __launch_bounds__(256) void k_lsm(float* __restrict__ out0) {
  __shared__ float rm[256];
  __shared__ float rs[256];
  const int row = blockIdx.x, tid = threadIdx.x;
  float4* p = (float4*)(out0 + (size_t)row * V_);
  float m = -INFINITY, s = 0.f;
  for (int i = tid; i < V_ / 4; i += 256) {
    const float4 v = p[i];
    const float mx = fmaxf(fmaxf(v.x, v.y), fmaxf(v.z, v.w));
    if (mx > m) { s *= __expf(m - mx); m = mx; }
    s += __expf(v.x - m) + __expf(v.y - m) + __expf(v.z - m) + __expf(v.w - m);
  }
  rm[tid] = m; rs[tid] = s;
  __syncthreads();
  for (int off = 128; off > 0; off >>= 1) {
    if (tid < off) {
      const float m2 = rm[tid + off], s2 = rs[tid + off];
      const float M = fmaxf(rm[tid], m2);
      rs[tid] = rs[tid] * __expf(rm[tid] - M) + s2 * __expf(m2 - M);
      rm[tid] = M;
    }
    __syncthreads();
  }
  const float lse = rm[0] + __logf(rs[0]);
  for (int i = tid; i < V_ / 4; i += 256) {
    float4 v = p[i];
    v.x -= lse; v.y -= lse; v.z -= lse; v.w -= lse;
    p[i] = v;
  }
}

__global__ __launch_bounds__(256) void k_copy(const float* __restrict__ src,
    float* __restrict__ dst, int n) {
  const int i = blockIdx.x * 256 + threadIdx.x;
  if (i < n) dst[i] = src[i];
}

// ---------------- host ----------------

extern "C" void kernel_launch(void* const* d_in, const int* in_sizes, int n_in,
                              void* d_out, int out_size, void* d_ws, size_t ws_size,
                              hipStream_t stream) {
  (void)in_sizes; (void)n_in; (void)out_size; (void)ws_size;
  const float* enc  = (const float*)d_in[0];
  const float* ehs  = (const float*)d_in[1];
  const int*   tgt  = (const int*)d_in[2];
  const float* emb  = (const float*)d_in[3];
  const float* Wq   = (const float*)d_in[4];
  const float* bq   = (const float*)d_in[5];
  const float* Wk   = (const float*)d_in[6];
  const float* bk   = (const float*)d_in[7];
  const float* Wv   = (const float*)d_in[8];
  const float* bv   = (const float*)d_in[9];
  const float* W_ih = (const float*)d_in[10];
  const float* W_hh = (const float*)d_in[11];
  const float* b_ih = (const float*)d_in[12];
  const float* b_hh = (const float*)d_in[13];
  const float* Wo   = (const float*)d_in[14];
  const float* bo   = (const float*)d_in[15];

  float* out0 = (float*)d_out;                          // log_probs [B*T, V]
  float* out1 = out0 + (size_t)B_ * T_ * V_;            // h_final [B*H]
  float* out2 = out1 + (size_t)B_ * H_;                 // attentions [B*T, S]

  // out0 doubles as scratch before the final GEMM overwrites it
  float* kproj   = out0;                  // 1,048,576
  float* giemb   = out0 + 1048576;        // 3,145,728
  float* emb_all = out0 + 4194304;        // 1,048,576
  float* W2      = out0 + 5242880;        // 1,572,864
  float* WqT     = out0 + 6815744;        // 262,144

  float* ws_f = (float*)d_ws;
  float* hbuf0 = ws_f;                    // 16384
  float* hbuf1 = ws_f + 16384;            // 16384
  float* ctx   = ws_f + 32768;            // 16384
  int*   flags = (int*)(ws_f + 49152);    // 64 ints
  __hip_bfloat16* Hall = (__hip_bfloat16*)(ws_f + 65536);  // 2048*512 bf16

  k_emb_gather<<<2048, 256, 0, stream>>>(tgt, emb, emb_all);
  k_pack_w2<<<1536, 256, 0, stream>>>(W_ih, W_hh, W2);
  k_transpose_wq<<<512, 256, 0, stream>>>(Wq, WqT);
  k_init<<<64, 256, 0, stream>>>(ehs, hbuf0, flags);

  {
    dim3 g(H_ / 64, (B_ * S_) / 64);      // kproj: M=2048, N=512, K=512
    k_gemm_f32<<<g, 256, 0, stream>>>(enc, 512, Wk, 512, bk, kproj, 512, 512);
  }
  {
    dim3 g(1536 / 64, (T_ * B_) / 64);    // gi_emb: M=2048, N=1536, K=512 (ldb=1024)
    k_gemm_f32<<<g, 256, 0, stream>>>(emb_all, 512, W_ih, 1024, b_ih, giemb, 1536, 512);
  }

  for (int t = 0; t < T_; ++t) {
    const float* hc = (t & 1) ? hbuf1 : hbuf0;
    float* hn = (t & 1) ? hbuf0 : hbuf1;
    k_step<<<288, 256, 0, stream>>>(t, hc, hn, kproj, enc, WqT, bq, Wv, bv,
                                    giemb, W2, b_hh, ctx, out2, Hall, flags);
  }

  {
    dim3 g(V_ / 128, (T_ * B_) / 128);    // (250, 16)
    k_logits<<<g, 256, 0, stream>>>(Hall, Wo, bo, out0);
  }
  k_lsm<<<(B_ * T_), 256, 0, stream>>>(out0);
  k_copy<<<64, 256, 0, stream>>>(hbuf0, out1, B_ * H_);  // after 64 steps, final h is in hbuf0
}

// Round 2
// 3578.742 us; speedup vs baseline: 4.1484x; 4.1484x over previous
//
#include <hip/hip_runtime.h>
#include <hip/hip_bf16.h>

#define B_ 32
#define S_ 64
#define H_ 512
#define V_ 32000
#define T_ 64

typedef __bf16 bf16x8 __attribute__((ext_vector_type(8)));
typedef float f32x4 __attribute__((ext_vector_type(4)));

__device__ __forceinline__ float fast_tanh(float x) {
  float e = __expf(2.0f * x);
  return 1.0f - 2.0f / (e + 1.0f);
}
__device__ __forceinline__ float fast_sigmoid(float x) {
  return 1.0f / (1.0f + __expf(-x));
}

// ---------------- prep kernels ----------------

__global__ __launch_bounds__(256) void k_emb_gather(const int* __restrict__ target,
    const float* __restrict__ emb, float* __restrict__ emb_all) {
  int row = blockIdx.x;                 // t*32 + b
  int t = row >> 5, b = row & 31;
  int tok = (t == 0) ? 0 : target[b * T_ + t - 1];
  const float* src = emb + (size_t)tok * H_;
  float* dst = emb_all + (size_t)row * H_;
  for (int j = threadIdx.x; j < H_; j += 256) dst[j] = src[j];
}

__global__ __launch_bounds__(256) void k_init(const float* __restrict__ ehs,
    float* __restrict__ h_glob) {
  int i = blockIdx.x * 256 + threadIdx.x;
  if (i < B_ * H_) h_glob[i] = ehs[i];
}

// ---------------- generic fp32 GEMM: C[M,N] = A[M,K] @ B[N,K]^T + bias ----------------

__global__ __launch_bounds__(256) void k_gemm_f32(
    const float* __restrict__ A, int lda,
    const float* __restrict__ B, int ldb,
    const float* __restrict__ bias,
    float* __restrict__ C, int ldc, int K) {
  __shared__ float As[16][64];
  __shared__ float Bs[16][64];
  const int tid = threadIdx.x;
  const int tx = tid & 15, ty = tid >> 4;
  const int m0 = blockIdx.y * 64, n0 = blockIdx.x * 64;
  const int r = tid >> 2, c4 = (tid & 3) * 4;
  float acc[4][4] = {};
  for (int k0 = 0; k0 < K; k0 += 16) {
    const float4 av = *(const float4*)(A + (size_t)(m0 + r) * lda + k0 + c4);
    const float4 bv = *(const float4*)(B + (size_t)(n0 + r) * ldb + k0 + c4);
    __syncthreads();
    As[c4 + 0][r] = av.x; As[c4 + 1][r] = av.y; As[c4 + 2][r] = av.z; As[c4 + 3][r] = av.w;
    Bs[c4 + 0][r] = bv.x; Bs[c4 + 1][r] = bv.y; Bs[c4 + 2][r] = bv.z; Bs[c4 + 3][r] = bv.w;
    __syncthreads();
#pragma unroll
    for (int k = 0; k < 16; ++k) {
      const float4 a = *(const float4*)(&As[k][ty * 4]);
      const float4 b = *(const float4*)(&Bs[k][tx * 4]);
      const float a4[4] = {a.x, a.y, a.z, a.w};
      const float b4[4] = {b.x, b.y, b.z, b.w};
#pragma unroll
      for (int i = 0; i < 4; ++i)
#pragma unroll
        for (int j = 0; j < 4; ++j)
          acc[i][j] = fmaf(a4[i], b4[j], acc[i][j]);
    }
  }
  const float4 bb = *(const float4*)(bias + n0 + tx * 4);
#pragma unroll
  for (int i = 0; i < 4; ++i) {
    float4 o;
    o.x = acc[i][0] + bb.x; o.y = acc[i][1] + bb.y;
    o.z = acc[i][2] + bb.z; o.w = acc[i][3] + bb.w;
    *(float4*)(C + (size_t)(m0 + ty * 4 + i) * ldc + n0 + tx * 4) = o;
  }
}

// ---------------- K1: qgh[b][row] = h[b] . [Wq; W_hh][row] (+bq for q rows) ----------------
// 256 blocks x 256 thr; block covers 8 rows; thread (r, kc): kc-slice of 16.

__global__ __launch_bounds__(256) void k1_hproj(
    const float* __restrict__ Wq, const float* __restrict__ W_hh,
    const float* __restrict__ bq,
    const float* __restrict__ h_glob, float* __restrict__ qgh) {
  const int tid = threadIdx.x;
  const int r = tid >> 5, kc = tid & 31;
  const int row = blockIdx.x * 8 + r;
  const float* wrow = (row < 512) ? (Wq + (size_t)row * 512)
                                  : (W_hh + (size_t)(row - 512) * 512);
  float4 w4[4];
#pragma unroll
  for (int i = 0; i < 4; ++i) w4[i] = *(const float4*)(wrow + kc * 16 + i * 4);
  const float bias = (row < 512) ? bq[row] : 0.f;
  for (int b = 0; b < B_; ++b) {
    const float* hb = h_glob + b * 512 + kc * 16;
    float p = 0.f;
#pragma unroll
    for (int i = 0; i < 4; ++i) {
      const float4 h4 = *(const float4*)(hb + i * 4);
      p += w4[i].x * h4.x + w4[i].y * h4.y + w4[i].z * h4.z + w4[i].w * h4.w;
    }
#pragma unroll
    for (int d = 16; d > 0; d >>= 1) p += __shfl_xor(p, d, 32);
    if (kc == 0) qgh[b * 2048 + row] = p + bias;
  }
}

// ---------------- K2: scores+softmax+ctx (redundant per js) + gic slice + combine ----------------
// grid (js=8, b=32), 256 thr.

__global__ __launch_bounds__(256) void k2_step(
    int t,
    const float* __restrict__ qgh,
    const float* __restrict__ kproj, const float* __restrict__ enc,
    const float* __restrict__ Wv, const float* __restrict__ bv,
    const float* __restrict__ W_ih,
    const float* __restrict__ giemb, const float* __restrict__ b_hh,
    float* __restrict__ h_glob,
    float* __restrict__ attn_out, __hip_bfloat16* __restrict__ Hall,
    float* __restrict__ hfin) {
  __shared__ float q_s[512];
  __shared__ float red[256];
  __shared__ float w_s[64];
  __shared__ float ctx_s[512];
  __shared__ float gic_s[192];
  const int tid = threadIdx.x;
  const int js = blockIdx.x;            // 0..7
  const int b  = blockIdx.y;            // 0..31

  q_s[tid]       = qgh[b * 2048 + tid];
  q_s[tid + 256] = qgh[b * 2048 + 256 + tid];
  __syncthreads();

  // scores: 4 threads per s, 128 h each
  {
    const int s = tid >> 2, part = tid & 3;
    const float* kp = kproj + ((size_t)(b * S_ + s)) * H_ + part * 128;
    const float* qp = q_s + part * 128;
    const float* wp = Wv + part * 128;
    float sc = 0.f;
    for (int k = 0; k < 128; k += 4) {
      const float4 kv = *(const float4*)(kp + k);
      const float4 qv = *(const float4*)(qp + k);
      const float4 wv = *(const float4*)(wp + k);
      sc = fmaf(wv.x, fast_tanh(qv.x + kv.x), sc);
      sc = fmaf(wv.y, fast_tanh(qv.y + kv.y), sc);
      sc = fmaf(wv.z, fast_tanh(qv.z + kv.z), sc);
      sc = fmaf(wv.w, fast_tanh(qv.w + kv.w), sc);
    }
    red[tid] = sc;
  }
  __syncthreads();
  if (tid < 64) {
    float sc = red[tid * 4] + red[tid * 4 + 1] + red[tid * 4 + 2] + red[tid * 4 + 3] + bv[0];
    float m = sc;
#pragma unroll
    for (int d = 32; d > 0; d >>= 1) m = fmaxf(m, __shfl_xor(m, d, 64));
    const float e = __expf(sc - m);
    float sum = e;
#pragma unroll
    for (int d = 32; d > 0; d >>= 1) sum += __shfl_xor(sum, d, 64);
    const float w = e / sum;
    w_s[tid] = w;
    if (js == 0) attn_out[((size_t)b * T_ + t) * S_ + tid] = w;
  }
  __syncthreads();

  // ctx
#pragma unroll
  for (int jj = 0; jj < 2; ++jj) {
    const int j = tid + jj * 256;
    float a = 0.f;
    const float* ep = enc + (size_t)(b * S_) * H_ + j;
    for (int s = 0; s < S_; ++s) a = fmaf(w_s[s], ep[s * 512], a);
    ctx_s[j] = a;
  }
  __syncthreads();

  // gic: 192 rows {g*512 + js*64 + h'}
  if (tid < 192) {
    const int g = tid >> 6, hp = tid & 63;
    const float* wr = W_ih + (size_t)(g * 512 + js * 64 + hp) * 1024 + 512;
    float a = 0.f;
    for (int k = 0; k < 512; k += 4) {
      const float4 wv = *(const float4*)(wr + k);
      const float4 cv = *(const float4*)(ctx_s + k);
      a += wv.x * cv.x + wv.y * cv.y + wv.z * cv.z + wv.w * cv.w;
    }
    gic_s[tid] = a;
  }
  __syncthreads();

  // combine
  if (tid < 64) {
    const int hh = js * 64 + tid;
    const size_t grow = ((size_t)t * B_ + b) * 1536;
    const int gbase = b * 2048 + 512;
    const float gir = giemb[grow + hh]        + gic_s[tid];
    const float giz = giemb[grow + 512 + hh]  + gic_s[64 + tid];
    const float gin = giemb[grow + 1024 + hh] + gic_s[128 + tid];
    const float ghr = qgh[gbase + hh]         + b_hh[hh];
    const float ghz = qgh[gbase + 512 + hh]   + b_hh[512 + hh];
    const float ghn = qgh[gbase + 1024 + hh]  + b_hh[1024 + hh];
    const float rg = fast_sigmoid(gir + ghr);
    const float zg = fast_sigmoid(giz + ghz);
    const float ng = fast_tanh(gin + rg * ghn);
    const float ho = h_glob[b * 512 + hh];
    const float hv = (1.f - zg) * ng + zg * ho;
    h_glob[b * 512 + hh] = hv;
    Hall[((size_t)b * T_ + t) * H_ + hh] = __float2bfloat16(hv);
    if (t == T_ - 1) hfin[b * 512 + hh] = hv;
  }
}

// ---------------- logits GEMM: out[m, :] = Hall[m, :] @ Wo^T + bo (bf16 MFMA) ----------------
// m = b*64+t (Hall and out0 share row order). grid (16 m-tiles, 250 n-tiles).

__global__ __launch_bounds__(256) void k_logits(
    const __hip_bfloat16* __restrict__ Hall, const float* __restrict__ Wo,
    const float* __restrict__ bo, float* __restrict__ out0) {
  __shared__ __hip_bfloat16 Asub[128 * 32];
  __shared__ __hip_bfloat16 Bsub[128 * 32];
  const int tid = threadIdx.x;
  const int lane = tid & 63, wave = tid >> 6;
  const int wr = wave >> 1, wc = wave & 1;
  const int m0 = blockIdx.x * 128, n0 = blockIdx.y * 128;
  f32x4 acc[4][4];
#pragma unroll
  for (int i = 0; i < 4; ++i)
#pragma unroll
    for (int j = 0; j < 4; ++j) acc[i][j] = (f32x4){0.f, 0.f, 0.f, 0.f};

  for (int k0 = 0; k0 < 512; k0 += 32) {
    uint4 a_v[2];
#pragma unroll
    for (int r = 0; r < 2; ++r) {
      const int seg = tid + r * 256;
      const int row = seg >> 2, ks8 = (seg & 3) * 8;
      a_v[r] = *(const uint4*)(Hall + (size_t)(m0 + row) * 512 + k0 + ks8);
    }
    float4 b_v[4];
#pragma unroll
    for (int r = 0; r < 4; ++r) {
      const int idx = tid + r * 256;
      const int n = idx >> 3, kg = (idx & 7) * 4;
      b_v[r] = *(const float4*)(Wo + (size_t)(n0 + n) * 512 + k0 + kg);
    }
    __syncthreads();
#pragma unroll
    for (int r = 0; r < 2; ++r) {
      const int seg = tid + r * 256;
      *(uint4*)(Asub + seg * 8) = a_v[r];
    }
#pragma unroll
    for (int r = 0; r < 4; ++r) {
      const int idx = tid + r * 256;
      const int n = idx >> 3, kg = (idx & 7) * 4;
      union { __hip_bfloat16 h[4]; uint2 u; } cv;
      cv.h[0] = __float2bfloat16(b_v[r].x);
      cv.h[1] = __float2bfloat16(b_v[r].y);
      cv.h[2] = __float2bfloat16(b_v[r].z);
      cv.h[3] = __float2bfloat16(b_v[r].w);
      *(uint2*)(Bsub + n * 32 + kg) = cv.u;
    }
    __syncthreads();
    bf16x8 af[4], bfr[4];
#pragma unroll
    for (int mi = 0; mi < 4; ++mi)
      af[mi] = *(const bf16x8*)(Asub + (wr * 64 + mi * 16 + (lane & 15)) * 32 + (lane >> 4) * 8);
#pragma unroll
    for (int ni = 0; ni < 4; ++ni)
      bfr[ni] = *(const bf16x8*)(Bsub + (wc * 64 + ni * 16 + (lane & 15)) * 32 + (lane >> 4) * 8);
#pragma unroll
    for (int mi = 0; mi < 4; ++mi)
#pragma unroll
      for (int ni = 0; ni < 4; ++ni)
        acc[mi][ni] = __builtin_amdgcn_mfma_f32_16x16x32_bf16(af[mi], bfr[ni], acc[mi][ni], 0, 0, 0);
  }
  const int r4 = (lane >> 4) * 4, cc = lane & 15;
#pragma unroll
  for (int ni = 0; ni < 4; ++ni) {
    const int col = n0 + wc * 64 + ni * 16 + cc;
    const float bias = bo[col];
#pragma unroll
    for (int mi = 0; mi < 4; ++mi) {
#pragma unroll
      for (int i = 0; i < 4; ++i) {
        const int mrow = m0 + wr * 64 + mi * 16 + r4 + i;
        out0[(size_t)mrow * V_ + col] = acc[mi][ni][i] + bias;
      }
    }
  }
}

// ---------------- in-place log_softmax over V, one row per block ----------------

__global__ __launch_bounds__(256) void k_lsm(float* __restrict__ out0) {
  __shared__ float rm[256];
  __shared__ float rs[256];
  const int row = blockIdx.x, tid = threadIdx.x;
  float4* p = (float4*)(out0 + (size_t)row * V_);
  float m = -INFINITY, s = 0.f;
  for (int i = tid; i < V_ / 4; i += 256) {
    const float4 v = p[i];
    const float mx = fmaxf(fmaxf(v.x, v.y), fmaxf(v.z, v.w));
    if (mx > m) { s *= __expf(m - mx); m = mx; }
    s += __expf(v.x - m) + __expf(v.y - m) + __expf(v.z - m) + __expf(v.w - m);
  }
  rm[tid] = m; rs[tid] = s;
  __syncthreads();
  for (int off = 128; off > 0; off >>= 1) {
    if (tid < off) {
      const float m2 = rm[tid + off], s2 = rs[tid + off];
      const float M = fmaxf(rm[tid], m2);
      rs[tid] = rs[tid] * __expf(rm[tid] - M) + s2 * __expf(m2 - M);
      rm[tid] = M;
    }
    __syncthreads();
  }
  const float lse = rm[0] + __logf(rs[0]);
  for (int i = tid; i < V_ / 4; i += 256) {
    float4 v = p[i];
    v.x -= lse; v.y -= lse; v.z -= lse; v.w -= lse;
    p[i] = v;
  }
}

// ---------------- host ----------------

extern "C" void kernel_launch(void* const* d_in, const int* in_sizes, int n_in,
                              void* d_out, int out_size, void* d_ws, size_t ws_size,
                              hipStream_t stream) {
  (void)in_sizes; (void)n_in; (void)out_size; (void)ws_size;
  const float* enc  = (const float*)d_in[0];
  const float* ehs  = (const float*)d_in[1];
  const int*   tgt  = (const int*)d_in[2];
  const float* emb  = (const float*)d_in[3];
  const float* Wq   = (const float*)d_in[4];
  const float* bq   = (const float*)d_in[5];
  const float* Wk   = (const float*)d_in[6];
  const float* bk   = (const float*)d_in[7];
  const float* Wv   = (const float*)d_in[8];
  const float* bv   = (const float*)d_in[9];
  const float* W_ih = (const float*)d_in[10];
  const float* W_hh = (const float*)d_in[11];
  const float* b_ih = (const float*)d_in[12];
  const float* b_hh = (const float*)d_in[13];
  const float* Wo   = (const float*)d_in[14];
  const float* bo   = (const float*)d_in[15];

  float* out0 = (float*)d_out;                          // log_probs [B*T, V]
  float* out1 = out0 + (size_t)B_ * T_ * V_;            // h_final [B*H]
  float* out2 = out1 + (size_t)B_ * H_;                 // attentions [B*T, S]

  // out0 doubles as scratch; k_logits overwrites it afterwards.
  float* kproj   = out0;                  // 1,048,576 floats
  float* giemb   = out0 + 1048576;        // 3,145,728
  float* emb_all = out0 + 4194304;        // 1,048,576
  float* h_glob  = out0 + 5242880;        // 16,384
  float* qgh     = out0 + 5259264;        // 65,536

  __hip_bfloat16* Hall = (__hip_bfloat16*)d_ws;         // 2048*512 bf16 = 2 MB

  k_emb_gather<<<2048, 256, 0, stream>>>(tgt, emb, emb_all);
  k_init<<<64, 256, 0, stream>>>(ehs, h_glob);

  {
    dim3 g(H_ / 64, (B_ * S_) / 64);      // kproj: M=2048, N=512, K=512
    k_gemm_f32<<<g, 256, 0, stream>>>(enc, 512, Wk, 512, bk, kproj, 512, 512);
  }
  {
    dim3 g(1536 / 64, (T_ * B_) / 64);    // gi_emb: M=2048, N=1536, K=512
    k_gemm_f32<<<g, 256, 0, stream>>>(emb_all, 512, W_ih, 1024, b_ih, giemb, 1536, 512);
  }

  for (int t = 0; t < T_; ++t) {
    k1_hproj<<<256, 256, 0, stream>>>(Wq, W_hh, bq, h_glob, qgh);
    k2_step<<<dim3(8, 32), 256, 0, stream>>>(t, qgh, kproj, enc, Wv, bv, W_ih,
                                             giemb, b_hh, h_glob, out2, Hall, out1);
  }

  {
    dim3 g((T_ * B_) / 128, V_ / 128);    // (16, 250): m fastest for Wo L2 reuse
    k_logits<<<g, 256, 0, stream>>>(Hall, Wo, bo, out0);
  }
  k_lsm<<<(B_ * T_), 256, 0, stream>>>(out0);
}